// Round 2
// baseline (207.605 us; speedup 1.0000x reference)
//
#include <hip/hip_runtime.h>
#include <hip/hip_bf16.h>

// Problem constants (from reference setup_inputs): B=8, C=3, H=W=512
#define HW    262144        // 512*512 (2^18)
#define HW4   65536         // HW/4 float4 elements per channel
#define BC    24            // B*C channels
#define NB    256           // bins
#define NTOT  6291456       // B*C*H*W

// Workspace layout (bytes):
//   [0, 24576)          hist_s : int[24][256]
//   [24576, 49152)      hist_r : int[24][256]
//   [49152, 49156)      accum  : float
//   [49216, 73792)      lut    : float[24][256]   (64-aligned)
//   [73792, 12656704)   code   : u16[24][262144]  (16-aligned)  (m<<8)|q
#define WS_HS_OFF   0
#define WS_HR_OFF   24576
#define WS_ACC_OFF  49152
#define WS_LUT_OFF  49216
#define WS_CODE_OFF 73792
#define WS_ZERO_BYTES 49156           // hs + hr + accum
#define WS_NEED     (WS_CODE_OFF + (size_t)BC * HW * 2)

__device__ __forceinline__ int quantize(float x, float m) {
    // jnp.clip(jnp.round((x+1)*0.5*255 * m), 0, 255)
    float v = (x + 1.0f) * 0.5f * 255.0f * m;
    float r = rintf(v);
    r = fminf(fmaxf(r, 0.0f), 255.0f);
    return (int)r;
}

// ---------------- Stage 1: per-channel histograms (+ code emission) ---------
// grid: dim3(64, 24), block: 256.  float4 loads; mask==0 lanes (all -> bin 0)
// counted via ballot+popcount to avoid hot-bin LDS-atomic serialization.
template <bool EMIT_CODE>
__global__ void hist_kernel(const float4* __restrict__ ref4,
                            const float4* __restrict__ tar4,
                            const float4* __restrict__ ms4,
                            const float4* __restrict__ mt4,
                            int* __restrict__ hs, int* __restrict__ hr,
                            ushort* __restrict__ code) {
    __shared__ int lhs[NB];
    __shared__ int lhr[NB];
    const int t = threadIdx.x;
    lhs[t] = 0;
    lhr[t] = 0;
    __syncthreads();

    const int c = blockIdx.y;
    const int b = c / 3;
    const float4* refc = ref4 + (size_t)c * HW4;
    const float4* tarc = tar4 + (size_t)c * HW4;
    const float4* msb  = ms4 + (size_t)b * HW4;
    const float4* mtb  = mt4 + (size_t)b * HW4;
    ushort4* codec = (ushort4*)(code + (size_t)c * HW);

    const int lane = t & 63;
    const int stride = gridDim.x * blockDim.x;

    for (int i = blockIdx.x * blockDim.x + t; i < HW4; i += stride) {
        const float4 r = refc[i];
        const float4 m = msb[i];
        const float4 tv = tarc[i];
        const float4 mm = mtb[i];

        const float rv[4] = {r.x, r.y, r.z, r.w};
        const float mv[4] = {m.x, m.y, m.z, m.w};
        const float tvv[4] = {tv.x, tv.y, tv.z, tv.w};
        const float mtv[4] = {mm.x, mm.y, mm.z, mm.w};

        ushort cw[4];
#pragma unroll
        for (int k = 0; k < 4; ++k) {
            const bool msk = (mv[k] != 0.0f);
            const int qs = quantize(rv[k], mv[k]);
            // mask==0 -> qs==0; count those once per wave
            unsigned long long bal = __ballot(!msk);
            if (lane == 0 && bal) atomicAdd(&lhs[0], __popcll(bal));
            if (msk) atomicAdd(&lhs[qs], 1);
            cw[k] = (ushort)(qs | (msk ? 0x100 : 0));

            const bool mskt = (mtv[k] != 0.0f);
            const int qr = quantize(tvv[k], mtv[k]);
            unsigned long long balt = __ballot(!mskt);
            if (lane == 0 && balt) atomicAdd(&lhr[0], __popcll(balt));
            if (mskt) atomicAdd(&lhr[qr], 1);
        }
        if (EMIT_CODE) {
            ushort4 cv;
            cv.x = cw[0]; cv.y = cw[1]; cv.z = cw[2]; cv.w = cw[3];
            codec[i] = cv;
        }
    }
    __syncthreads();
    if (lhs[t]) atomicAdd(&hs[c * NB + t], lhs[t]);
    if (lhr[t]) atomicAdd(&hr[c * NB + t], lhr[t]);
}

// ---------------- Stage 2: per-channel matching LUT ----------------
__device__ __forceinline__ int incl_scan256(int v, int t, int* buf) {
    buf[t] = v;
    __syncthreads();
#pragma unroll
    for (int off = 1; off < NB; off <<= 1) {
        int x = (t >= off) ? buf[t - off] : 0;
        __syncthreads();
        buf[t] += x;
        __syncthreads();
    }
    return buf[t];
}

__global__ void lut_kernel(const int* __restrict__ hs,
                           const int* __restrict__ hr,
                           float* __restrict__ lut) {
    const int c = blockIdx.x;
    const int t = threadIdx.x;

    __shared__ int buf[NB];
    __shared__ float xp[NB];
    __shared__ float fp[NB];
    __shared__ int firstS, firstR, nOccS, nOccR;

    const int cs = hs[c * NB + t];
    const int cr = hr[c * NB + t];

    if (t == 0) { firstS = NB; firstR = NB; nOccS = 0; nOccR = 0; }
    __syncthreads();
    if (cs > 0) { atomicMin(&firstS, t); atomicAdd(&nOccS, 1); }
    if (cr > 0) { atomicMin(&firstR, t); atomicAdd(&nOccR, 1); }
    __syncthreads();

    const int csz = (t == firstS) ? 0 : cs;
    const int crz = (t == firstR) ? 0 : cr;

    const int cumS = incl_scan256(csz, t, buf);
    const int totS = buf[NB - 1];
    __syncthreads();
    const int cumR = incl_scan256(crz, t, buf);
    const int totR = buf[NB - 1];
    __syncthreads();
    const int occ2 = (cr > 0 && t != firstR) ? 1 : 0;
    const int rank = incl_scan256(occ2, t, buf) - occ2;  // exclusive
    __syncthreads();

    const float x  = (float)cumS / fmaxf((float)totS, 1.0f);
    const float rq = (float)cumR / fmaxf((float)totR, 1.0f);

    xp[t] = 2.0f;
    fp[t] = 0.0f;
    __syncthreads();
    if (occ2) { xp[rank] = rq; fp[rank] = (float)t; }
    __syncthreads();

    // jnp.interp semantics
    int lo = 0, hi = NB;
    while (lo < hi) {
        int mid = (lo + hi) >> 1;
        if (xp[mid] > x) hi = mid; else lo = mid + 1;
    }
    int i = lo;
    i = (i < 1) ? 1 : ((i > NB - 1) ? NB - 1 : i);
    float dxv = xp[i] - xp[i - 1];
    float f;
    if (dxv == 0.0f) f = fp[i];
    else f = fp[i - 1] + (x - xp[i - 1]) / dxv * (fp[i] - fp[i - 1]);
    if (x < xp[0]) f = fp[0];

    float l = truncf(f);
    if (t == firstS) l = 0.0f;
    const bool ok = (nOccS > 1) && (nOccR > 1);
    if (!ok) l = 0.0f;

    lut[c * NB + t] = l;
}

// ---------------- Stage 3a: loss from code array ----------------
// grid: dim3(256, 24); one channel per blockIdx.y; LUT staged in LDS.
__global__ void loss_code_kernel(const float4* __restrict__ inp4,
                                 const ushort4* __restrict__ code4,
                                 const float* __restrict__ lut,
                                 float* __restrict__ accum) {
    __shared__ float llut[NB];
    const int t = threadIdx.x;
    const int c = blockIdx.y;
    llut[t] = lut[c * NB + t];
    __syncthreads();

    const int i = blockIdx.x * blockDim.x + t;   // 0..HW4-1
    const float4 x = inp4[(size_t)c * HW4 + i];
    const ushort4 cd = code4[(size_t)c * HW4 + i];

    float s = 0.0f;
    const float xv[4] = {x.x, x.y, x.z, x.w};
    const ushort cv[4] = {cd.x, cd.y, cd.z, cd.w};
#pragma unroll
    for (int k = 0; k < 4; ++k) {
        if (cv[k] & 0x100) {
            const float im = (xv[k] + 1.0f) * 127.5f;
            s += fabsf(im - llut[cv[k] & 0xFF]);
        }
    }

#pragma unroll
    for (int off = 32; off > 0; off >>= 1) s += __shfl_down(s, off);
    __shared__ float wsum[4];
    const int lane = t & 63;
    const int wave = t >> 6;
    if (lane == 0) wsum[wave] = s;
    __syncthreads();
    if (t == 0) atomicAdd(accum, wsum[0] + wsum[1] + wsum[2] + wsum[3]);
}

// ---------------- Stage 3b: fallback (re-read ref+msrc) ----------------
__global__ void loss_ref_kernel(const float4* __restrict__ inp4,
                                const float4* __restrict__ ref4,
                                const float4* __restrict__ ms4,
                                const float* __restrict__ lut,
                                float* __restrict__ accum) {
    __shared__ float llut[NB];
    const int t = threadIdx.x;
    const int c = blockIdx.y;
    const int b = c / 3;
    llut[t] = lut[c * NB + t];
    __syncthreads();

    const int i = blockIdx.x * blockDim.x + t;
    const float4 x = inp4[(size_t)c * HW4 + i];
    const float4 r = ref4[(size_t)c * HW4 + i];
    const float4 m = ms4[(size_t)b * HW4 + i];

    float s = 0.0f;
    const float xv[4] = {x.x, x.y, x.z, x.w};
    const float rv[4] = {r.x, r.y, r.z, r.w};
    const float mv[4] = {m.x, m.y, m.z, m.w};
#pragma unroll
    for (int k = 0; k < 4; ++k) {
        if (mv[k] != 0.0f) {
            const int q = quantize(rv[k], mv[k]);
            const float im = (xv[k] + 1.0f) * 127.5f;
            s += fabsf(im - llut[q]);
        }
    }

#pragma unroll
    for (int off = 32; off > 0; off >>= 1) s += __shfl_down(s, off);
    __shared__ float wsum[4];
    const int lane = t & 63;
    const int wave = t >> 6;
    if (lane == 0) wsum[wave] = s;
    __syncthreads();
    if (t == 0) atomicAdd(accum, wsum[0] + wsum[1] + wsum[2] + wsum[3]);
}

__global__ void finalize_kernel(const float* __restrict__ accum,
                                float* __restrict__ out) {
    out[0] = accum[0] / (float)NTOT;
}

extern "C" void kernel_launch(void* const* d_in, const int* in_sizes, int n_in,
                              void* d_out, int out_size, void* d_ws, size_t ws_size,
                              hipStream_t stream) {
    const float* inp  = (const float*)d_in[0];
    const float* tar  = (const float*)d_in[1];
    const float* ref  = (const float*)d_in[2];
    const float* msrc = (const float*)d_in[3];
    const float* mtar = (const float*)d_in[4];

    char* ws = (char*)d_ws;
    int*    hs    = (int*)(ws + WS_HS_OFF);
    int*    hr    = (int*)(ws + WS_HR_OFF);
    float*  accum = (float*)(ws + WS_ACC_OFF);
    float*  lut   = (float*)(ws + WS_LUT_OFF);
    ushort* code  = (ushort*)(ws + WS_CODE_OFF);

    hipMemsetAsync(d_ws, 0, WS_ZERO_BYTES, stream);

    const bool use_code = (ws_size >= WS_NEED);

    if (use_code) {
        hist_kernel<true><<<dim3(64, BC), 256, 0, stream>>>(
            (const float4*)ref, (const float4*)tar,
            (const float4*)msrc, (const float4*)mtar, hs, hr, code);
    } else {
        hist_kernel<false><<<dim3(64, BC), 256, 0, stream>>>(
            (const float4*)ref, (const float4*)tar,
            (const float4*)msrc, (const float4*)mtar, hs, hr, nullptr);
    }

    lut_kernel<<<BC, 256, 0, stream>>>(hs, hr, lut);

    if (use_code) {
        loss_code_kernel<<<dim3(HW4 / 256, BC), 256, 0, stream>>>(
            (const float4*)inp, (const ushort4*)code, lut, accum);
    } else {
        loss_ref_kernel<<<dim3(HW4 / 256, BC), 256, 0, stream>>>(
            (const float4*)inp, (const float4*)ref, (const float4*)msrc,
            lut, accum);
    }

    finalize_kernel<<<1, 1, 0, stream>>>(accum, (float*)d_out);
}